// Round 7
// baseline (101.694 us; speedup 1.0000x reference)
//
#include <hip/hip_runtime.h>
#include <hip/hip_bf16.h>

// EmbeddingPredictor: B=16 T=2048 V=32000 E=512 H=4 C=3, f32 in/out.
// R7: BM=32 fused blocks, geometry fixed (R6 was inconsistent):
//   256 threads (4 waves). Wave w: ctx for 8 tokens (rows 8w..8w+7, 10-row halo,
//   f32 dots + shfl reduce = R5's proven phase 1), GEMM cols [128w,128w+128)
//   (acc[2][8]). A-tile 32x512 bf16 swizzled LDS (32KB) -> 4 blocks/CU.
//  K0 prep: Pt[3][512] f32; Wb = bf16(ffn_w)
// ws: Pt @0 (6KB), Wb @8KB (512KB).

#define Bq 16
#define Tq 2048
#define Eq 512
#define Cq 3
#define Hq 4
#define Mq (Bq * Tq)
#define LN_EPS 1e-5f

typedef __attribute__((ext_vector_type(8))) short bf16x8;
typedef __attribute__((ext_vector_type(4))) float f32x4;

__device__ __forceinline__ unsigned short f2bf(float f) {
    unsigned int u = __float_as_uint(f);
    u += 0x7fffu + ((u >> 16) & 1u);   // round-to-nearest-even
    return (unsigned short)(u >> 16);
}
__device__ __forceinline__ unsigned int cvt_pk_bf16(float lo, float hi) {
    unsigned int r;
    asm("v_cvt_pk_bf16_f32 %0, %1, %2" : "=v"(r) : "v"(lo), "v"(hi));
    return r;   // low16 = bf16(lo), high16 = bf16(hi), RNE
}
// swizzled LDS byte address within a [row][1024B] tile
__device__ __forceinline__ int xaddr(int row, int kbyte) {
    return row * 1024 + (kbyte ^ ((row & 7) << 4));
}

// ---------------- K0: prep ----------------
__global__ void prep_kernel(const float* __restrict__ pos,
                            const float* __restrict__ ffn_w,
                            float* __restrict__ Pt,            // [C][E]
                            unsigned short* __restrict__ Wb) { // [E][E] bf16
    int i = blockIdx.x * blockDim.x + threadIdx.x;
    if (i < Cq * Eq) {
        int c = i / Eq, e = i % Eq;
        float s = 0.f;
#pragma unroll
        for (int h = 0; h < Hq; ++h) s += pos[(h * Eq + e) * Cq + c];
        Pt[i] = s;
    }
    int nth = blockDim.x * gridDim.x;
    for (int j = i; j < Eq * Eq; j += nth) Wb[j] = f2bf(ffn_w[j]);
}

// ---------------- K1: fused ctx + FFN GEMM + bias + LayerNorm + swish ----------------
// grid = M/32 = 1024 blocks, 256 threads (4 waves). Block owns tokens m0..m0+31.
// Wave w: ctx tokens m0+8w..m0+8w+7; GEMM cols [128w, 128w+128), rows 0..31.
__global__ __launch_bounds__(256, 4) void fused_kernel(const int* __restrict__ tokens,
                                                       const float* __restrict__ tbl,
                                                       const float* __restrict__ Pt,
                                                       const unsigned short* __restrict__ Wb,
                                                       const float* __restrict__ bias,
                                                       const float* __restrict__ ln_g,
                                                       const float* __restrict__ ln_b,
                                                       float* __restrict__ out) {
    __shared__ __align__(16) unsigned short Atile[32 * 512];   // 32KB, swizzled bf16
    __shared__ float lds_sum[32][4];
    __shared__ float lds_sq[32][4];
    __shared__ float lds_mu[32];
    __shared__ float lds_rs[32];

    const int tid = threadIdx.x;
    const int wave = tid >> 6;
    const int lane = tid & 63;
    const int lr = lane & 15;
    const int lg = lane >> 4;
    const int m0 = blockIdx.x << 5;
    const int t0w = (m0 & (Tq - 1)) + (wave << 3);
    const int tb = (m0 >> 11) << 11;
    char* Xc = reinterpret_cast<char*>(Atile);

    const int n0 = wave << 7;
    const short* Bp = reinterpret_cast<const short*>(Wb) + (long)n0 * Eq;

    // ---- phase 1a: gather 10 rows (8 tokens + 2 halo) in f32 regs ----
    float x[10][8];
#pragma unroll
    for (int li = 0; li < 10; ++li) {
        const int t = t0w - 2 + li;
        float4 v0 = {0.f, 0.f, 0.f, 0.f}, v1 = {0.f, 0.f, 0.f, 0.f};
        if (t >= 0) {
            const int tok = tokens[tb + t];
            const float4* rp = reinterpret_cast<const float4*>(tbl + (long)tok * Eq + lane * 8);
            v0 = rp[0]; v1 = rp[1];
        }
        x[li][0] = v0.x; x[li][1] = v0.y; x[li][2] = v0.z; x[li][3] = v0.w;
        x[li][4] = v1.x; x[li][5] = v1.y; x[li][6] = v1.z; x[li][7] = v1.w;
    }

    // ---- phase 1b: f32 dots (valid iff 0 <= li-c <= 7) + wave reduce ----
    float d[10][Cq];
#pragma unroll
    for (int c = 0; c < Cq; ++c) {
        const float4* pp = reinterpret_cast<const float4*>(Pt + c * Eq + lane * 8);
        const float4 p0 = pp[0], p1 = pp[1];
#pragma unroll
        for (int li = 0; li < 10; ++li) {
            if (li >= c && li - c <= 7) {
                d[li][c] = x[li][0] * p0.x + x[li][1] * p0.y + x[li][2] * p0.z + x[li][3] * p0.w
                         + x[li][4] * p1.x + x[li][5] * p1.y + x[li][6] * p1.z + x[li][7] * p1.w;
            }
        }
    }
#pragma unroll
    for (int li = 0; li < 10; ++li)
#pragma unroll
        for (int c = 0; c < Cq; ++c)
            if (li >= c && li - c <= 7) {
#pragma unroll
                for (int m = 1; m < 64; m <<= 1) d[li][c] += __shfl_xor(d[li][c], m, 64);
            }

    // ---- phase 1c: combination -> cvt_pk -> swizzled LDS A-tile (rows 8w..8w+7) ----
    const float inv = 1.f / (Hq * Cq);
#pragma unroll
    for (int jj = 0; jj < 8; ++jj) {
        const float s0 = d[jj][0] * inv, s1 = d[jj + 1][1] * inv, s2 = d[jj + 2][2] * inv;
        float a[8];
#pragma unroll
        for (int e = 0; e < 8; ++e)
            a[e] = s0 * x[jj][e] + s1 * x[jj + 1][e] + s2 * x[jj + 2][e];
        uint4 o;
        o.x = cvt_pk_bf16(a[0], a[1]);
        o.y = cvt_pk_bf16(a[2], a[3]);
        o.z = cvt_pk_bf16(a[4], a[5]);
        o.w = cvt_pk_bf16(a[6], a[7]);
        const int row = (wave << 3) + jj;
        *reinterpret_cast<uint4*>(Xc + xaddr(row, lane * 16)) = o;
    }
    __syncthreads();

    // ---- phase 2: GEMM, no inner barriers; A (32 rows) from LDS, B (128 cols) from L2 ----
    f32x4 acc[2][8];
#pragma unroll
    for (int i = 0; i < 2; ++i)
#pragma unroll
        for (int j = 0; j < 8; ++j) acc[i][j] = (f32x4){0.f, 0.f, 0.f, 0.f};

#pragma unroll
    for (int kb = 0; kb < 8; ++kb) {
#pragma unroll
        for (int ks = 0; ks < 2; ++ks) {
            bf16x8 af[2], bfv[8];
#pragma unroll
            for (int nf = 0; nf < 8; ++nf)
                bfv[nf] = *reinterpret_cast<const bf16x8*>(Bp + (nf * 16 + lr) * Eq + kb * 64 + ks * 32 + lg * 8);
#pragma unroll
            for (int mf = 0; mf < 2; ++mf)
                af[mf] = *reinterpret_cast<const bf16x8*>(Xc + xaddr(mf * 16 + lr, kb * 128 + ks * 64 + lg * 16));
#pragma unroll
            for (int mf = 0; mf < 2; ++mf)
#pragma unroll
                for (int nf = 0; nf < 8; ++nf)
                    acc[mf][nf] = __builtin_amdgcn_mfma_f32_16x16x32_bf16(af[mf], bfv[nf], acc[mf][nf], 0, 0, 0);
        }
    }

    // ---- epilogue: bias + LayerNorm + swish ----
    float bcol[8];
#pragma unroll
    for (int nf = 0; nf < 8; ++nf) bcol[nf] = bias[n0 + nf * 16 + lr];

#pragma unroll
    for (int mf = 0; mf < 2; ++mf) {
#pragma unroll
        for (int i = 0; i < 4; ++i) {
            float sm = 0.f, sq = 0.f;
#pragma unroll
            for (int nf = 0; nf < 8; ++nf) {
                float v = acc[mf][nf][i] + bcol[nf];
                acc[mf][nf][i] = v;
                sm += v;
                sq += v * v;
            }
#pragma unroll
            for (int msk = 1; msk < 16; msk <<= 1) {
                sm += __shfl_xor(sm, msk, 64);
                sq += __shfl_xor(sq, msk, 64);
            }
            if (lr == 0) {
                const int row = mf * 16 + lg * 4 + i;
                lds_sum[row][wave] = sm;
                lds_sq[row][wave] = sq;
            }
        }
    }
    __syncthreads();
    if (tid < 32) {
        float sm = 0.f, sq = 0.f;
#pragma unroll
        for (int w = 0; w < 4; ++w) { sm += lds_sum[tid][w]; sq += lds_sq[tid][w]; }
        const float mu = sm * (1.f / Eq);
        const float var = sq * (1.f / Eq) - mu * mu;
        lds_mu[tid] = mu;
        lds_rs[tid] = rsqrtf(var + LN_EPS);
    }
    __syncthreads();

    float gcol[8], bbcol[8];
#pragma unroll
    for (int nf = 0; nf < 8; ++nf) {
        gcol[nf] = ln_g[n0 + nf * 16 + lr];
        bbcol[nf] = ln_b[n0 + nf * 16 + lr];
    }
#pragma unroll
    for (int mf = 0; mf < 2; ++mf) {
#pragma unroll
        for (int i = 0; i < 4; ++i) {
            const int row = mf * 16 + lg * 4 + i;
            const float mu = lds_mu[row];
            const float rs = lds_rs[row];
#pragma unroll
            for (int nf = 0; nf < 8; ++nf) {
                float v = acc[mf][nf][i];
                float o = (v - mu) * rs * gcol[nf] + bbcol[nf];
                o = o / (1.f + __expf(-o));   // swish
                out[(long)(m0 + row) * Eq + (n0 + nf * 16 + lr)] = o;
            }
        }
    }
}

extern "C" void kernel_launch(void* const* d_in, const int* in_sizes, int n_in,
                              void* d_out, int out_size, void* d_ws, size_t ws_size,
                              hipStream_t stream) {
    const int* tokens = (const int*)d_in[0];
    const float* tbl = (const float*)d_in[1];
    const float* pos = (const float*)d_in[2];
    const float* ffn_w = (const float*)d_in[3];
    const float* ffn_b = (const float*)d_in[4];
    const float* ln_g = (const float*)d_in[5];
    const float* ln_b = (const float*)d_in[6];
    float* out = (float*)d_out;

    char* ws = (char*)d_ws;
    float* Pt = (float*)ws;                              // 6 KB
    unsigned short* Wb = (unsigned short*)(ws + 8192);   // 512 KB

    hipLaunchKernelGGL(prep_kernel, dim3(64), dim3(256), 0, stream, pos, ffn_w, Pt, Wb);
    hipLaunchKernelGGL(fused_kernel, dim3(Mq / 32), dim3(256), 0, stream,
                       tokens, tbl, Pt, Wb, ffn_b, ln_g, ln_b, out);
}